// Round 4
// baseline (1840.709 us; speedup 1.0000x reference)
//
#include <hip/hip_runtime.h>

typedef unsigned int u32;

// ---- sizes ----
// out region offsets (fp32 elements)
#define OUT0_N   50331648ll     // 96*1024*512
#define MEAN_SM  50331648ll
#define MEAN_AT  51118080ll     // + 786432

// ---------------------------------------------------------------------------
// C[m,n] = maybe_prelu( sum_c A[m,c] * W[n,c] ),  K = 512 fixed, fp32 out.
// BM=BN=128, BK=16, 256 threads, 8x8 acc per thread.
// ---------------------------------------------------------------------------
template<int PRELU>
__global__ __launch_bounds__(256)
void gemm_nt(const float* __restrict__ A, const float* __restrict__ W,
             float* __restrict__ C, int N, const float* __restrict__ paPtr)
{
  __shared__ float lA[16][132];
  __shared__ float lW[16][132];
  const int tid = threadIdx.x;
  const int m0 = blockIdx.y * 128;
  const int n0 = blockIdx.x * 128;
  const int ty = tid >> 4;   // 0..15 -> rows ty*8..ty*8+7
  const int tx = tid & 15;   // cols tx*4..+3 and 64+tx*4..+3

  float acc[8][8];
#pragma unroll
  for (int i = 0; i < 8; ++i)
#pragma unroll
    for (int j = 0; j < 8; ++j) acc[i][j] = 0.0f;

  for (int k0 = 0; k0 < 512; k0 += 16) {
#pragma unroll
    for (int r = 0; r < 2; ++r) {
      int idx = tid + r * 256;            // 0..511
      int row = idx >> 2;                 // 0..127
      int c4  = (idx & 3) << 2;           // 0,4,8,12
      float4 va = *reinterpret_cast<const float4*>(A + (size_t)(m0 + row) * 512 + k0 + c4);
      lA[c4 + 0][row] = va.x; lA[c4 + 1][row] = va.y;
      lA[c4 + 2][row] = va.z; lA[c4 + 3][row] = va.w;
      float4 vw = *reinterpret_cast<const float4*>(W + (size_t)(n0 + row) * 512 + k0 + c4);
      lW[c4 + 0][row] = vw.x; lW[c4 + 1][row] = vw.y;
      lW[c4 + 2][row] = vw.z; lW[c4 + 3][row] = vw.w;
    }
    __syncthreads();
#pragma unroll
    for (int kk = 0; kk < 16; ++kk) {
      float4 a0 = *reinterpret_cast<const float4*>(&lA[kk][ty * 8]);
      float4 a1 = *reinterpret_cast<const float4*>(&lA[kk][ty * 8 + 4]);
      float4 w0 = *reinterpret_cast<const float4*>(&lW[kk][tx * 4]);
      float4 w1 = *reinterpret_cast<const float4*>(&lW[kk][64 + tx * 4]);
      float av[8] = {a0.x, a0.y, a0.z, a0.w, a1.x, a1.y, a1.z, a1.w};
      float wv[8] = {w0.x, w0.y, w0.z, w0.w, w1.x, w1.y, w1.z, w1.w};
#pragma unroll
      for (int i = 0; i < 8; ++i)
#pragma unroll
        for (int j = 0; j < 8; ++j)
          acc[i][j] += av[i] * wv[j];
    }
    __syncthreads();
  }

  const float pa = PRELU ? paPtr[0] : 0.0f;
#pragma unroll
  for (int i = 0; i < 8; ++i) {
    int m = m0 + ty * 8 + i;
    float v[8];
#pragma unroll
    for (int j = 0; j < 8; ++j) {
      float x = acc[i][j];
      v[j] = (PRELU && x < 0.0f) ? pa * x : x;
    }
    *reinterpret_cast<float4*>(C + (size_t)m * N + n0 + tx * 4)      = make_float4(v[0], v[1], v[2], v[3]);
    *reinterpret_cast<float4*>(C + (size_t)m * N + n0 + 64 + tx * 4) = make_float4(v[4], v[5], v[6], v[7]);
  }
}

// ---------------------------------------------------------------------------
// Attention per batch b (fp32 end-to-end): scores (96x8) per head, mask/scale,
// softmax over flattened 768, out_pre = sm @ v written fp32 in place over the
// Q slice, head-means to regions 1,2.
// ---------------------------------------------------------------------------
__global__ __launch_bounds__(256)
void attn_kernel(const float* __restrict__ KV, float* __restrict__ O)
{
  const int b   = blockIdx.x;
  const int tid = threadIdx.x;

  __shared__ float kv[8][1028];     // k: [*][0:512), v: [*][512:1024)
  __shared__ float qh[96][68];
  __shared__ float sc[96][8];
  __shared__ float am[768];
  __shared__ float asmv[768];
  __shared__ float red[4];

  // stage KV[.,b,.]
#pragma unroll
  for (int r = 0; r < 8; ++r) {
    int idx = tid + r * 256;               // 2048 float4 loads
    int sk = idx >> 8;
    int j4 = (idx & 255) << 2;
    float4 v = *reinterpret_cast<const float4*>(KV + ((size_t)(sk * 1024 + b)) * 1024 + j4);
    *reinterpret_cast<float4*>(&kv[sk][j4]) = v;
  }
  for (int idx = tid; idx < 768; idx += 256) { am[idx] = 0.0f; asmv[idx] = 0.0f; }
  __syncthreads();

  const float scale = 0.04419417382415922f;   // 512^-0.5

  for (int h = 0; h < 8; ++h) {
    // stage q_h (fp32)
#pragma unroll
    for (int r = 0; r < 6; ++r) {
      int idx = tid + r * 256;             // 1536 float4 loads
      int q  = idx >> 4;
      int d4 = (idx & 15) << 2;
      float4 u = *reinterpret_cast<const float4*>(O + ((size_t)(q * 1024 + b)) * 512 + h * 64 + d4);
      qh[q][d4 + 0] = u.x;
      qh[q][d4 + 1] = u.y;
      qh[q][d4 + 2] = u.z;
      qh[q][d4 + 3] = u.w;
    }
    __syncthreads();

    // scores: 3 per thread
    float s[3];
#pragma unroll
    for (int r = 0; r < 3; ++r) {
      int idx = tid + r * 256;
      int q  = idx >> 3;
      int kk = idx & 7;
      float a = 0.0f;
#pragma unroll
      for (int d = 0; d < 64; d += 4) {
        float4 qa = *reinterpret_cast<const float4*>(&qh[q][d]);
        float4 ka = *reinterpret_cast<const float4*>(&kv[kk][h * 64 + d]);
        a += qa.x * ka.x + qa.y * ka.y + qa.z * ka.z + qa.w * ka.w;
      }
      if (a == 0.0f) a -= 10000.0f;        // reference mask semantics
      s[r] = a * scale;
      am[idx] += s[r] * 0.125f;
    }

    // block max over 768
    float mx = fmaxf(fmaxf(s[0], s[1]), s[2]);
#pragma unroll
    for (int off = 32; off; off >>= 1) mx = fmaxf(mx, __shfl_xor(mx, off));
    if ((tid & 63) == 0) red[tid >> 6] = mx;
    __syncthreads();
    const float Mx = fmaxf(fmaxf(red[0], red[1]), fmaxf(red[2], red[3]));
    __syncthreads();

    float e0 = __expf(s[0] - Mx), e1 = __expf(s[1] - Mx), e2 = __expf(s[2] - Mx);
    float ls = e0 + e1 + e2;
#pragma unroll
    for (int off = 32; off; off >>= 1) ls += __shfl_xor(ls, off);
    if ((tid & 63) == 0) red[tid >> 6] = ls;
    __syncthreads();
    const float T = red[0] + red[1] + red[2] + red[3];
    const float inv = 1.0f / T;

    {
      float sm0 = e0 * inv, sm1 = e1 * inv, sm2 = e2 * inv;
      int i0 = tid, i1 = tid + 256, i2 = tid + 512;
      sc[i0 >> 3][i0 & 7] = sm0;
      sc[i1 >> 3][i1 & 7] = sm1;
      sc[i2 >> 3][i2 & 7] = sm2;
      asmv[i0] += sm0 * 0.125f;
      asmv[i1] += sm1 * 0.125f;
      asmv[i2] += sm2 * 0.125f;
    }
    __syncthreads();

    // out_pre = sm @ v  (96 x 64), written fp32 in place of the Q slice
#pragma unroll
    for (int r = 0; r < 12; ++r) {
      int idx = tid + r * 256;             // < 3072, 2 outputs each
      int q  = idx >> 5;
      int d2 = (idx & 31) << 1;
      float a0 = 0.0f, a1 = 0.0f;
#pragma unroll
      for (int kk = 0; kk < 8; ++kk) {
        float smv = sc[q][kk];
        a0 += smv * kv[kk][512 + h * 64 + d2];
        a1 += smv * kv[kk][512 + h * 64 + d2 + 1];
      }
      float2 pk; pk.x = a0; pk.y = a1;
      *reinterpret_cast<float2*>(O + ((size_t)(q * 1024 + b)) * 512 + h * 64 + d2) = pk;
    }
    __syncthreads();
  }

  // head means (fp32)
  const size_t base1 = MEAN_SM + (size_t)b * 768;
  const size_t base2 = MEAN_AT + (size_t)b * 768;
  for (int idx = tid; idx < 768; idx += 256) {
    O[base1 + idx] = asmv[idx];
    O[base2 + idx] = am[idx];
  }
}

// ---------------------------------------------------------------------------
// out = out_pre @ Wpost^T, in place over d_out region 0 (fp32 in/out).
// One wg owns 32 full rows (reads complete before its writes; rows disjoint
// across wgs -> no cross-wg hazard).
// ---------------------------------------------------------------------------
__global__ __launch_bounds__(256)
void gemm_post(float* __restrict__ C, const float* __restrict__ W)
{
  __shared__ float lA[16][36];
  __shared__ float lW[16][513];
  const int tid = threadIdx.x;
  const int m0 = blockIdx.x * 32;
  const int ty = tid >> 6;   // 0..3 -> rows ty*8..+7
  const int tx = tid & 63;   // cols tx + 64*j

  float acc[8][8];
#pragma unroll
  for (int i = 0; i < 8; ++i)
#pragma unroll
    for (int j = 0; j < 8; ++j) acc[i][j] = 0.0f;

  for (int k0 = 0; k0 < 512; k0 += 16) {
    {
      int row = tid >> 3;                  // 0..31
      int c2  = (tid & 7) << 1;            // 0,2,..,14
      float2 v = *reinterpret_cast<const float2*>(C + (size_t)(m0 + row) * 512 + k0 + c2);
      lA[c2][row]     = v.x;
      lA[c2 + 1][row] = v.y;
    }
#pragma unroll
    for (int r = 0; r < 8; ++r) {
      int idx = tid + r * 256;             // 2048 float4
      int n  = idx >> 2;                   // 0..511
      int c4 = (idx & 3) << 2;
      float4 vw = *reinterpret_cast<const float4*>(W + (size_t)n * 512 + k0 + c4);
      lW[c4 + 0][n] = vw.x; lW[c4 + 1][n] = vw.y;
      lW[c4 + 2][n] = vw.z; lW[c4 + 3][n] = vw.w;
    }
    __syncthreads();
#pragma unroll
    for (int kk = 0; kk < 16; ++kk) {
      float4 a0 = *reinterpret_cast<const float4*>(&lA[kk][ty * 8]);
      float4 a1 = *reinterpret_cast<const float4*>(&lA[kk][ty * 8 + 4]);
      float av[8] = {a0.x, a0.y, a0.z, a0.w, a1.x, a1.y, a1.z, a1.w};
      float wv[8];
#pragma unroll
      for (int j = 0; j < 8; ++j) wv[j] = lW[kk][tx + 64 * j];
#pragma unroll
      for (int i = 0; i < 8; ++i)
#pragma unroll
        for (int j = 0; j < 8; ++j)
          acc[i][j] += av[i] * wv[j];
    }
    __syncthreads();
  }

#pragma unroll
  for (int i = 0; i < 8; ++i) {
    int m = m0 + ty * 8 + i;
#pragma unroll
    for (int j = 0; j < 8; ++j)
      C[(size_t)m * 512 + tx + 64 * j] = acc[i][j];
  }
}

// ---------------------------------------------------------------------------
extern "C" void kernel_launch(void* const* d_in, const int* in_sizes, int n_in,
                              void* d_out, int out_size, void* d_ws, size_t ws_size,
                              hipStream_t stream)
{
  (void)in_sizes; (void)n_in; (void)out_size; (void)ws_size;
  const float* ipt   = (const float*)d_in[0];
  const float* Wq    = (const float*)d_in[1];
  const float* Wkv   = (const float*)d_in[2];
  const float* Wpost = (const float*)d_in[3];
  const float* pa    = (const float*)d_in[4];
  float* out  = (float*)d_out;
  float* kvws = (float*)d_ws;          // 8192 x 1024 f32 = 32 MiB

  // Q = prelu(ipt[0:96] @ Wq^T) -> fp32 into d_out region 0 (scratch)
  gemm_nt<1><<<dim3(4, 768), 256, 0, stream>>>(ipt, Wq, out, 512, pa);
  // KV = prelu(ipt[96:104] @ Wkv^T) -> fp32 into ws
  gemm_nt<1><<<dim3(8, 64), 256, 0, stream>>>(ipt + 50331648ll, Wkv, kvws, 1024, pa);
  // attention + softmax + out_pre (in place) + head means
  attn_kernel<<<1024, 256, 0, stream>>>(kvws, out);
  // out = out_pre @ Wpost^T (in place, fp32)
  gemm_post<<<3072, 256, 0, stream>>>(out, Wpost);
}

// Round 5
// 640.402 us; speedup vs baseline: 2.8743x; 2.8743x over previous
//
#include <hip/hip_runtime.h>
#include <hip/hip_bf16.h>

typedef unsigned int u32;
typedef unsigned short u16;
typedef __attribute__((ext_vector_type(8))) short bf16x8;
typedef __attribute__((ext_vector_type(4))) float f32x4;

// d_out fp32 element offsets
#define MEAN_SM  50331648ll
#define MEAN_AT  51118080ll
// d_ws u16 offsets: [KV bf16 8192x1024][Wq bf16][Wkv bf16][Wpost bf16]
#define KV_OFF    0ll
#define WQ_OFF    8388608ll
#define WKV_OFF   8650752ll
#define WPOST_OFF 9175040ll

__device__ __forceinline__ u16 f2bf(float x){
  u32 u = __float_as_uint(x);
  return (u16)((u + 0x7fffu + ((u >> 16) & 1u)) >> 16);   // RNE
}
__device__ __forceinline__ float bf2f(u32 s){ return __uint_as_float(s << 16); }
__device__ __forceinline__ u32 cvt2(float x, float y){
  __hip_bfloat162 h = __float22bfloat162_rn(make_float2(x, y));   // v_cvt_pk_bf16_f32
  u32 r; __builtin_memcpy(&r, &h, 4); return r;
}

// ---------------------------------------------------------------------------
// fp32 -> bf16 elementwise (weights pre-convert). n8 = elems/8.
// ---------------------------------------------------------------------------
__global__ __launch_bounds__(256)
void conv_bf16(const float* __restrict__ src, u16* __restrict__ dst, int n8)
{
  int c = blockIdx.x * 256 + threadIdx.x;
  if (c < n8) {
    float4 f0 = *reinterpret_cast<const float4*>(src + (size_t)c * 8);
    float4 f1 = *reinterpret_cast<const float4*>(src + (size_t)c * 8 + 4);
    uint4 p = make_uint4(cvt2(f0.x, f0.y), cvt2(f0.z, f0.w),
                         cvt2(f1.x, f1.y), cvt2(f1.z, f1.w));
    *reinterpret_cast<uint4*>(dst + (size_t)c * 8) = p;
  }
}

// ---------------------------------------------------------------------------
// MFMA GEMM: C[m,n] = prelu( sum_k A[m,k] * W[n,k] ), K=512.
// A fp32 (cvt to bf16 during staging), W already bf16 [N][512].
// BM=BN=128, BK=64, 256 thr = 4 waves (2x2, each 64x64 via 4x4 16x16 tiles).
// OBF16: C is u16 bf16, else fp32.
// ---------------------------------------------------------------------------
template<int OBF16, int PRELU>
__global__ __launch_bounds__(256)
void mfma_gemm(const float* __restrict__ A, const u16* __restrict__ Wb,
               void* __restrict__ Cout, int N, const float* __restrict__ paPtr)
{
  __shared__ u16 lA[128][72];   // 72*2=144B row stride (16B aligned, 2-way banks)
  __shared__ u16 lW[128][72];
  const int tid  = threadIdx.x;
  const int lane = tid & 63;
  const int wr   = (tid >> 7) & 1;       // wave row (2x2)
  const int wc   = (tid >> 6) & 1;       // wave col
  const int lr   = lane & 15;
  const int lk   = (lane >> 4) << 3;     // 0,8,16,24 : k-chunk per lane group
  const size_t m0 = (size_t)blockIdx.y * 128;
  const int n0 = blockIdx.x * 128;

  const f32x4 zero = {0.f, 0.f, 0.f, 0.f};
  f32x4 acc[4][4];
#pragma unroll
  for (int i = 0; i < 4; ++i)
#pragma unroll
    for (int j = 0; j < 4; ++j) acc[i][j] = zero;

  for (int k0 = 0; k0 < 512; k0 += 64) {
    // stage A 128x64 fp32 -> bf16 (fully coalesced: 16 thr per row-span)
#pragma unroll
    for (int i = 0; i < 8; ++i) {
      int c = tid + i * 256;             // 0..2047
      int row = c >> 4;
      int k4  = (c & 15) << 2;
      float4 f = *reinterpret_cast<const float4*>(A + (m0 + row) * 512 + k0 + k4);
      *reinterpret_cast<uint2*>(&lA[row][k4]) =
          make_uint2(cvt2(f.x, f.y), cvt2(f.z, f.w));
    }
    // stage W 128x64 bf16 (raw 16B copies)
#pragma unroll
    for (int i = 0; i < 4; ++i) {
      int c = tid + i * 256;             // 0..1023
      int row = c >> 3;
      int k8  = (c & 7) << 3;
      *reinterpret_cast<uint4*>(&lW[row][k8]) =
          *reinterpret_cast<const uint4*>(Wb + (size_t)(n0 + row) * 512 + k0 + k8);
    }
    __syncthreads();
#pragma unroll
    for (int ks = 0; ks < 2; ++ks) {
      bf16x8 af[4], bw[4];
#pragma unroll
      for (int t = 0; t < 4; ++t) {
        af[t] = *reinterpret_cast<const bf16x8*>(&lA[wr * 64 + t * 16 + lr][ks * 32 + lk]);
        bw[t] = *reinterpret_cast<const bf16x8*>(&lW[wc * 64 + t * 16 + lr][ks * 32 + lk]);
      }
#pragma unroll
      for (int mi = 0; mi < 4; ++mi)
#pragma unroll
        for (int nj = 0; nj < 4; ++nj)
          acc[mi][nj] = __builtin_amdgcn_mfma_f32_16x16x32_bf16(af[mi], bw[nj], acc[mi][nj], 0, 0, 0);
    }
    __syncthreads();
  }

  const float pa = PRELU ? paPtr[0] : 0.0f;
#pragma unroll
  for (int mi = 0; mi < 4; ++mi)
#pragma unroll
    for (int nj = 0; nj < 4; ++nj) {
#pragma unroll
      for (int j = 0; j < 4; ++j) {
        size_t r = m0 + wr * 64 + mi * 16 + ((lane >> 4) << 2) + j;  // C/D: row=(l>>4)*4+reg
        int cc = n0 + wc * 64 + nj * 16 + lr;                        //      col=l&15
        float x = acc[mi][nj][j];
        if (PRELU && x < 0.f) x *= pa;
        if (OBF16) ((u16*)Cout)[r * (size_t)N + cc] = f2bf(x);
        else       ((float*)Cout)[r * (size_t)N + cc] = x;
      }
    }
}

// ---------------------------------------------------------------------------
// Attention per batch b (fp32 compute): KV now bf16 [8192][1024].
// ---------------------------------------------------------------------------
__global__ __launch_bounds__(256)
void attn_kernel(const u16* __restrict__ KVb, float* __restrict__ O)
{
  const int b   = blockIdx.x;
  const int tid = threadIdx.x;

  __shared__ float kv[8][1028];     // k: [*][0:512), v: [*][512:1024)
  __shared__ float qh[96][68];
  __shared__ float sc[96][8];
  __shared__ float am[768];
  __shared__ float asmv[768];
  __shared__ float red[4];

  // stage KV[.,b,.] bf16 -> f32
#pragma unroll
  for (int i = 0; i < 4; ++i) {
    int c = tid + i * 256;               // 0..1023
    int sk = c >> 7;
    int j8 = (c & 127) << 3;
    uint4 u = *reinterpret_cast<const uint4*>(KVb + ((size_t)(sk * 1024 + b)) * 1024 + j8);
    kv[sk][j8 + 0] = bf2f(u.x & 0xffffu); kv[sk][j8 + 1] = bf2f(u.x >> 16);
    kv[sk][j8 + 2] = bf2f(u.y & 0xffffu); kv[sk][j8 + 3] = bf2f(u.y >> 16);
    kv[sk][j8 + 4] = bf2f(u.z & 0xffffu); kv[sk][j8 + 5] = bf2f(u.z >> 16);
    kv[sk][j8 + 6] = bf2f(u.w & 0xffffu); kv[sk][j8 + 7] = bf2f(u.w >> 16);
  }
  for (int idx = tid; idx < 768; idx += 256) { am[idx] = 0.0f; asmv[idx] = 0.0f; }
  __syncthreads();

  const float scale = 0.04419417382415922f;   // 512^-0.5

  for (int h = 0; h < 8; ++h) {
    // stage q_h (fp32)
#pragma unroll
    for (int r = 0; r < 6; ++r) {
      int idx = tid + r * 256;             // 1536 float4 loads
      int q  = idx >> 4;
      int d4 = (idx & 15) << 2;
      float4 u = *reinterpret_cast<const float4*>(O + ((size_t)(q * 1024 + b)) * 512 + h * 64 + d4);
      qh[q][d4 + 0] = u.x; qh[q][d4 + 1] = u.y;
      qh[q][d4 + 2] = u.z; qh[q][d4 + 3] = u.w;
    }
    __syncthreads();

    // scores: 3 per thread
    float s[3];
#pragma unroll
    for (int r = 0; r < 3; ++r) {
      int idx = tid + r * 256;
      int q  = idx >> 3;
      int kk = idx & 7;
      float a = 0.0f;
#pragma unroll
      for (int d = 0; d < 64; d += 4) {
        float4 qa = *reinterpret_cast<const float4*>(&qh[q][d]);
        float4 ka = *reinterpret_cast<const float4*>(&kv[kk][h * 64 + d]);
        a += qa.x * ka.x + qa.y * ka.y + qa.z * ka.z + qa.w * ka.w;
      }
      if (a == 0.0f) a -= 10000.0f;        // reference mask semantics
      s[r] = a * scale;
      am[idx] += s[r] * 0.125f;
    }

    // block max over 768
    float mx = fmaxf(fmaxf(s[0], s[1]), s[2]);
#pragma unroll
    for (int off = 32; off; off >>= 1) mx = fmaxf(mx, __shfl_xor(mx, off));
    if ((tid & 63) == 0) red[tid >> 6] = mx;
    __syncthreads();
    const float Mx = fmaxf(fmaxf(red[0], red[1]), fmaxf(red[2], red[3]));
    __syncthreads();

    float e0 = __expf(s[0] - Mx), e1 = __expf(s[1] - Mx), e2 = __expf(s[2] - Mx);
    float ls = e0 + e1 + e2;
#pragma unroll
    for (int off = 32; off; off >>= 1) ls += __shfl_xor(ls, off);
    if ((tid & 63) == 0) red[tid >> 6] = ls;
    __syncthreads();
    const float T = red[0] + red[1] + red[2] + red[3];
    const float inv = 1.0f / T;

    {
      float sm0 = e0 * inv, sm1 = e1 * inv, sm2 = e2 * inv;
      int i0 = tid, i1 = tid + 256, i2 = tid + 512;
      sc[i0 >> 3][i0 & 7] = sm0;
      sc[i1 >> 3][i1 & 7] = sm1;
      sc[i2 >> 3][i2 & 7] = sm2;
      asmv[i0] += sm0 * 0.125f;
      asmv[i1] += sm1 * 0.125f;
      asmv[i2] += sm2 * 0.125f;
    }
    __syncthreads();

    // out_pre = sm @ v  (96 x 64), fp32 in place over the Q slice
#pragma unroll
    for (int r = 0; r < 12; ++r) {
      int idx = tid + r * 256;
      int q  = idx >> 5;
      int d2 = (idx & 31) << 1;
      float a0 = 0.0f, a1 = 0.0f;
#pragma unroll
      for (int kk = 0; kk < 8; ++kk) {
        float smv = sc[q][kk];
        a0 += smv * kv[kk][512 + h * 64 + d2];
        a1 += smv * kv[kk][512 + h * 64 + d2 + 1];
      }
      float2 pk; pk.x = a0; pk.y = a1;
      *reinterpret_cast<float2*>(O + ((size_t)(q * 1024 + b)) * 512 + h * 64 + d2) = pk;
    }
    __syncthreads();
  }

  const size_t base1 = MEAN_SM + (size_t)b * 768;
  const size_t base2 = MEAN_AT + (size_t)b * 768;
  for (int idx = tid; idx < 768; idx += 256) {
    O[base1 + idx] = asmv[idx];
    O[base2 + idx] = am[idx];
  }
}

// ---------------------------------------------------------------------------
// out = out_pre @ Wpost^T, in place (fp32 in/out). MFMA bf16.
// BM=64 rows x full N=512 per wg (hazard-free), BK=32, 512 thr = 8 waves,
// wave w owns cols [w*64, w*64+64): 4x4 16x16 tiles.
// ---------------------------------------------------------------------------
__global__ __launch_bounds__(512)
void post_gemm(float* __restrict__ C, const u16* __restrict__ Wb)
{
  __shared__ u16 lA[64][40];    // 80B row stride
  __shared__ u16 lW[512][40];
  const int tid  = threadIdx.x;
  const int lane = tid & 63;
  const int w    = tid >> 6;           // 0..7
  const int lr   = lane & 15;
  const int lk   = (lane >> 4) << 3;   // 0,8,16,24
  const size_t m0 = (size_t)blockIdx.x * 64;

  const f32x4 zero = {0.f, 0.f, 0.f, 0.f};
  f32x4 acc[4][4];
#pragma unroll
  for (int i = 0; i < 4; ++i)
#pragma unroll
    for (int j = 0; j < 4; ++j) acc[i][j] = zero;

  for (int k0 = 0; k0 < 512; k0 += 32) {
    {  // stage A 64x32 fp32 -> bf16 (1 float4/thread)
      int row = tid >> 3;
      int k4  = (tid & 7) << 2;
      float4 f = *reinterpret_cast<const float4*>(C + (m0 + row) * 512 + k0 + k4);
      *reinterpret_cast<uint2*>(&lA[row][k4]) =
          make_uint2(cvt2(f.x, f.y), cvt2(f.z, f.w));
    }
    // stage W 512x32 bf16
#pragma unroll
    for (int i = 0; i < 4; ++i) {
      int c = tid + i * 512;           // 0..2047
      int n  = c >> 2;
      int k8 = (c & 3) << 3;
      *reinterpret_cast<uint4*>(&lW[n][k8]) =
          *reinterpret_cast<const uint4*>(Wb + (size_t)n * 512 + k0 + k8);
    }
    __syncthreads();
    bf16x8 af[4], bw[4];
#pragma unroll
    for (int t = 0; t < 4; ++t) {
      af[t] = *reinterpret_cast<const bf16x8*>(&lA[t * 16 + lr][lk]);
      bw[t] = *reinterpret_cast<const bf16x8*>(&lW[w * 64 + t * 16 + lr][lk]);
    }
#pragma unroll
    for (int mi = 0; mi < 4; ++mi)
#pragma unroll
      for (int nj = 0; nj < 4; ++nj)
        acc[mi][nj] = __builtin_amdgcn_mfma_f32_16x16x32_bf16(af[mi], bw[nj], acc[mi][nj], 0, 0, 0);
    __syncthreads();
  }

#pragma unroll
  for (int mi = 0; mi < 4; ++mi)
#pragma unroll
    for (int nj = 0; nj < 4; ++nj) {
#pragma unroll
      for (int j = 0; j < 4; ++j) {
        size_t r = m0 + mi * 16 + ((lane >> 4) << 2) + j;
        int cc = w * 64 + nj * 16 + lr;
        C[r * 512 + cc] = acc[mi][nj][j];
      }
    }
}

// ---------------------------------------------------------------------------
extern "C" void kernel_launch(void* const* d_in, const int* in_sizes, int n_in,
                              void* d_out, int out_size, void* d_ws, size_t ws_size,
                              hipStream_t stream)
{
  (void)in_sizes; (void)n_in; (void)out_size; (void)ws_size;
  const float* ipt   = (const float*)d_in[0];
  const float* Wq    = (const float*)d_in[1];
  const float* Wkv   = (const float*)d_in[2];
  const float* Wpost = (const float*)d_in[3];
  const float* pa    = (const float*)d_in[4];
  float* out = (float*)d_out;
  u16*   wsb = (u16*)d_ws;

  // weights -> bf16 (once per launch; tiny)
  conv_bf16<<<128, 256, 0, stream>>>(Wq,    wsb + WQ_OFF,    32768);
  conv_bf16<<<256, 256, 0, stream>>>(Wkv,   wsb + WKV_OFF,   65536);
  conv_bf16<<<128, 256, 0, stream>>>(Wpost, wsb + WPOST_OFF, 32768);

  // Q = prelu(ipt[0:96] @ Wq^T) -> fp32 into d_out region 0 (scratch)
  mfma_gemm<0, 1><<<dim3(4, 768), 256, 0, stream>>>(ipt, wsb + WQ_OFF, out, 512, pa);
  // KV = prelu(ipt[96:104] @ Wkv^T) -> bf16 into ws
  mfma_gemm<1, 1><<<dim3(8, 64), 256, 0, stream>>>(ipt + 50331648ll, wsb + WKV_OFF,
                                                   wsb + KV_OFF, 1024, pa);
  // attention + softmax + out_pre (in place) + head means
  attn_kernel<<<1024, 256, 0, stream>>>(wsb + KV_OFF, out);
  // out = out_pre @ Wpost^T (in place)
  post_gemm<<<1536, 512, 0, stream>>>(out, wsb + WPOST_OFF);
}

// Round 8
// 621.693 us; speedup vs baseline: 2.9608x; 1.0301x over previous
//
#include <hip/hip_runtime.h>
#include <hip/hip_bf16.h>

typedef unsigned int u32;
typedef unsigned short u16;
typedef __attribute__((ext_vector_type(8))) short bf16x8;
typedef __attribute__((ext_vector_type(4))) float f32x4;

// d_out fp32 element offsets for the two mean outputs
#define MEAN_SM  50331648ll
#define MEAN_AT  51118080ll
// d_ws u16 offsets: [KV bf16 8192x1024][Wq bf16][Wkv bf16][Wpost bf16]
#define KV_OFF    0ll
#define WQ_OFF    8388608ll
#define WKV_OFF   8650752ll
#define WPOST_OFF 9175040ll
// d_out region 0: 98304 row-slots of 2048 B. bf16 Q/out_pre row = first 1024 B
// of slot; final fp32 out row = full 2048 B of the same slot.
#define SLOT 2048ll

__device__ __forceinline__ u16 f2bf(float x){
  u32 u = __float_as_uint(x);
  return (u16)((u + 0x7fffu + ((u >> 16) & 1u)) >> 16);   // RNE
}
__device__ __forceinline__ float bf2f(u32 s){ return __uint_as_float(s << 16); }
__device__ __forceinline__ u32 cvt2(float x, float y){
  __hip_bfloat162 h = __float22bfloat162_rn(make_float2(x, y));   // v_cvt_pk_bf16_f32
  u32 r; __builtin_memcpy(&r, &h, 4); return r;
}

// ---------------------------------------------------------------------------
// fp32 -> bf16 elementwise (weights pre-convert). n8 = elems/8.
// ---------------------------------------------------------------------------
__global__ __launch_bounds__(256)
void conv_bf16(const float* __restrict__ src, u16* __restrict__ dst, int n8)
{
  int c = blockIdx.x * 256 + threadIdx.x;
  if (c < n8) {
    float4 f0 = *reinterpret_cast<const float4*>(src + (size_t)c * 8);
    float4 f1 = *reinterpret_cast<const float4*>(src + (size_t)c * 8 + 4);
    uint4 p = make_uint4(cvt2(f0.x, f0.y), cvt2(f0.z, f0.w),
                         cvt2(f1.x, f1.y), cvt2(f1.z, f1.w));
    *reinterpret_cast<uint4*>(dst + (size_t)c * 8) = p;
  }
}

// ---------------------------------------------------------------------------
// MFMA GEMM: C[m,n] = prelu( sum_k A[m,k] * W[n,k] ), K=512.
// A fp32 (cvt to bf16 during staging), W bf16 [N][512].
// BM=BN=128, BK=64, 256 thr = 4 waves (2x2, each 64x64 via 4x4 16x16 tiles).
// OMODE: 1 = bf16 linear (stride N), 2 = bf16 into 2048B-pitch slots.
// SWZ: 1 = 1D grid 3072, XCD-chunked so the 4 n-tiles of an m-panel share L2.
// ---------------------------------------------------------------------------
template<int OMODE, int PRELU, int SWZ>
__global__ __launch_bounds__(256)
void mfma_gemm(const float* __restrict__ A, const u16* __restrict__ Wb,
               void* __restrict__ Cout, int N, const float* __restrict__ paPtr)
{
  __shared__ u16 lA[128][72];
  __shared__ u16 lW[128][72];
  int bx, by;
  if (SWZ) {
    int L = blockIdx.x;        // 0..3071
    int x = L & 7;             // XCD (heuristic: round-robin dispatch)
    int j = L >> 3;            // 0..383 within XCD
    by = x * 96 + (j >> 2);    // m-panel: 96 consecutive panels per XCD
    bx = j & 3;                // 4 n-tiles of a panel adjacent in time, same L2
  } else { bx = blockIdx.x; by = blockIdx.y; }

  const int tid  = threadIdx.x;
  const int lane = tid & 63;
  const int wr   = (tid >> 7) & 1;
  const int wc   = (tid >> 6) & 1;
  const int lr   = lane & 15;
  const int lk   = (lane >> 4) << 3;
  const size_t m0 = (size_t)by * 128;
  const int n0 = bx * 128;

  const f32x4 zero = {0.f, 0.f, 0.f, 0.f};
  f32x4 acc[4][4];
#pragma unroll
  for (int i = 0; i < 4; ++i)
#pragma unroll
    for (int j = 0; j < 4; ++j) acc[i][j] = zero;

  for (int k0 = 0; k0 < 512; k0 += 64) {
#pragma unroll
    for (int i = 0; i < 8; ++i) {
      int c = tid + i * 256;
      int row = c >> 4;
      int k4  = (c & 15) << 2;
      float4 f = *reinterpret_cast<const float4*>(A + (m0 + row) * 512 + k0 + k4);
      *reinterpret_cast<uint2*>(&lA[row][k4]) =
          make_uint2(cvt2(f.x, f.y), cvt2(f.z, f.w));
    }
#pragma unroll
    for (int i = 0; i < 4; ++i) {
      int c = tid + i * 256;
      int row = c >> 3;
      int k8  = (c & 7) << 3;
      *reinterpret_cast<uint4*>(&lW[row][k8]) =
          *reinterpret_cast<const uint4*>(Wb + (size_t)(n0 + row) * 512 + k0 + k8);
    }
    __syncthreads();
#pragma unroll
    for (int ks = 0; ks < 2; ++ks) {
      bf16x8 af[4], bw[4];
#pragma unroll
      for (int t = 0; t < 4; ++t) {
        af[t] = *reinterpret_cast<const bf16x8*>(&lA[wr * 64 + t * 16 + lr][ks * 32 + lk]);
        bw[t] = *reinterpret_cast<const bf16x8*>(&lW[wc * 64 + t * 16 + lr][ks * 32 + lk]);
      }
#pragma unroll
      for (int mi = 0; mi < 4; ++mi)
#pragma unroll
        for (int nj = 0; nj < 4; ++nj)
          acc[mi][nj] = __builtin_amdgcn_mfma_f32_16x16x32_bf16(af[mi], bw[nj], acc[mi][nj], 0, 0, 0);
    }
    __syncthreads();
  }

  const float pa = PRELU ? paPtr[0] : 0.0f;
#pragma unroll
  for (int mi = 0; mi < 4; ++mi)
#pragma unroll
    for (int nj = 0; nj < 4; ++nj) {
#pragma unroll
      for (int j = 0; j < 4; ++j) {
        size_t r = m0 + wr * 64 + mi * 16 + ((lane >> 4) << 2) + j;  // row=(l>>4)*4+reg
        int cc = n0 + wc * 64 + nj * 16 + lr;                        // col=l&15
        float x = acc[mi][nj][j];
        if (PRELU && x < 0.f) x *= pa;
        if (OMODE == 1) ((u16*)Cout)[r * (size_t)N + cc] = f2bf(x);
        else            ((u16*)((char*)Cout + r * SLOT))[cc] = f2bf(x);
      }
    }
}

// ---------------------------------------------------------------------------
// Attention per batch b (fp32 compute). KV bf16 [8192][1024] in ws.
// Q bf16 in d_out slots; out_pre bf16 written in place over the Q slice.
// ---------------------------------------------------------------------------
__global__ __launch_bounds__(256)
void attn_kernel(const u16* __restrict__ KVb, char* __restrict__ Ob)
{
  const int b   = blockIdx.x;
  const int tid = threadIdx.x;

  __shared__ float kv[8][1028];     // k: [*][0:512), v: [*][512:1024)
  __shared__ float qh[96][68];
  __shared__ float sc[96][8];
  __shared__ float am[768];
  __shared__ float asmv[768];
  __shared__ float red[4];

#pragma unroll
  for (int i = 0; i < 4; ++i) {
    int c = tid + i * 256;
    int sk = c >> 7;
    int j8 = (c & 127) << 3;
    uint4 u = *reinterpret_cast<const uint4*>(KVb + ((size_t)(sk * 1024 + b)) * 1024 + j8);
    kv[sk][j8 + 0] = bf2f(u.x & 0xffffu); kv[sk][j8 + 1] = bf2f(u.x >> 16);
    kv[sk][j8 + 2] = bf2f(u.y & 0xffffu); kv[sk][j8 + 3] = bf2f(u.y >> 16);
    kv[sk][j8 + 4] = bf2f(u.z & 0xffffu); kv[sk][j8 + 5] = bf2f(u.z >> 16);
    kv[sk][j8 + 6] = bf2f(u.w & 0xffffu); kv[sk][j8 + 7] = bf2f(u.w >> 16);
  }
  for (int idx = tid; idx < 768; idx += 256) { am[idx] = 0.0f; asmv[idx] = 0.0f; }
  __syncthreads();

  const float scale = 0.04419417382415922f;   // 512^-0.5

  for (int h = 0; h < 8; ++h) {
    // stage q_h (bf16 slots -> f32 LDS)
#pragma unroll
    for (int r = 0; r < 6; ++r) {
      int idx = tid + r * 256;
      int q  = idx >> 4;
      int d4 = (idx & 15) << 2;
      const u16* qrow = (const u16*)(Ob + ((size_t)(q * 1024 + b)) * SLOT);
      uint2 u = *reinterpret_cast<const uint2*>(qrow + h * 64 + d4);
      qh[q][d4 + 0] = bf2f(u.x & 0xffffu); qh[q][d4 + 1] = bf2f(u.x >> 16);
      qh[q][d4 + 2] = bf2f(u.y & 0xffffu); qh[q][d4 + 3] = bf2f(u.y >> 16);
    }
    __syncthreads();

    float s[3];
#pragma unroll
    for (int r = 0; r < 3; ++r) {
      int idx = tid + r * 256;
      int q  = idx >> 3;
      int kk = idx & 7;
      float a = 0.0f;
#pragma unroll
      for (int d = 0; d < 64; d += 4) {
        float4 qa = *reinterpret_cast<const float4*>(&qh[q][d]);
        float4 ka = *reinterpret_cast<const float4*>(&kv[kk][h * 64 + d]);
        a += qa.x * ka.x + qa.y * ka.y + qa.z * ka.z + qa.w * ka.w;
      }
      if (a == 0.0f) a -= 10000.0f;        // reference mask semantics
      s[r] = a * scale;
      am[idx] += s[r] * 0.125f;
    }

    float mx = fmaxf(fmaxf(s[0], s[1]), s[2]);
#pragma unroll
    for (int off = 32; off; off >>= 1) mx = fmaxf(mx, __shfl_xor(mx, off));
    if ((tid & 63) == 0) red[tid >> 6] = mx;
    __syncthreads();
    const float Mx = fmaxf(fmaxf(red[0], red[1]), fmaxf(red[2], red[3]));
    __syncthreads();

    float e0 = __expf(s[0] - Mx), e1 = __expf(s[1] - Mx), e2 = __expf(s[2] - Mx);
    float ls = e0 + e1 + e2;
#pragma unroll
    for (int off = 32; off; off >>= 1) ls += __shfl_xor(ls, off);
    if ((tid & 63) == 0) red[tid >> 6] = ls;
    __syncthreads();
    const float T = red[0] + red[1] + red[2] + red[3];
    const float inv = 1.0f / T;

    {
      float sm0 = e0 * inv, sm1 = e1 * inv, sm2 = e2 * inv;
      int i0 = tid, i1 = tid + 256, i2 = tid + 512;
      sc[i0 >> 3][i0 & 7] = sm0;
      sc[i1 >> 3][i1 & 7] = sm1;
      sc[i2 >> 3][i2 & 7] = sm2;
      asmv[i0] += sm0 * 0.125f;
      asmv[i1] += sm1 * 0.125f;
      asmv[i2] += sm2 * 0.125f;
    }
    __syncthreads();

    // out_pre = sm @ v (96x64) -> bf16 in place over the Q slice
#pragma unroll
    for (int r = 0; r < 12; ++r) {
      int idx = tid + r * 256;
      int q  = idx >> 5;
      int d2 = (idx & 31) << 1;
      float a0 = 0.0f, a1 = 0.0f;
#pragma unroll
      for (int kk = 0; kk < 8; ++kk) {
        float smv = sc[q][kk];
        a0 += smv * kv[kk][512 + h * 64 + d2];
        a1 += smv * kv[kk][512 + h * 64 + d2 + 1];
      }
      u16* orow = (u16*)(Ob + ((size_t)(q * 1024 + b)) * SLOT);
      *reinterpret_cast<u32*>(orow + h * 64 + d2) = cvt2(a0, a1);
    }
    __syncthreads();
  }

  float* Of = (float*)Ob;
  const size_t base1 = MEAN_SM + (size_t)b * 768;
  const size_t base2 = MEAN_AT + (size_t)b * 768;
  for (int idx = tid; idx < 768; idx += 256) {
    Of[base1 + idx] = asmv[idx];
    Of[base2 + idx] = am[idx];
  }
}

// ---------------------------------------------------------------------------
// out = out_pre @ Wpost^T. out_pre bf16 in slots; out fp32 into the SAME
// slots (within-wg: all A reads precede writes; rows disjoint across wgs).
// BM=64 x N=512, BK=32, 512 thr = 8 waves; wave w owns cols [w*64,w*64+64).
// ---------------------------------------------------------------------------
__global__ __launch_bounds__(512)
void post_gemm(char* __restrict__ Cb, const u16* __restrict__ Wb)
{
  __shared__ u16 lA[64][40];
  __shared__ u16 lW[512][40];
  const int tid  = threadIdx.x;
  const int lane = tid & 63;
  const int w    = tid >> 6;
  const int lr   = lane & 15;
  const int lk   = (lane >> 4) << 3;
  const size_t m0 = (size_t)blockIdx.x * 64;

  const f32x4 zero = {0.f, 0.f, 0.f, 0.f};
  f32x4 acc[4][4];
#pragma unroll
  for (int i = 0; i < 4; ++i)
#pragma unroll
    for (int j = 0; j < 4; ++j) acc[i][j] = zero;

  for (int k0 = 0; k0 < 512; k0 += 32) {
    {  // stage A 64x32 bf16 from slots (1 uint2 = 4 u16 per thread)
      int row = tid >> 3;
      int k4  = (tid & 7) << 2;
      const u16* arow = (const u16*)(Cb + (m0 + row) * SLOT);
      *reinterpret_cast<uint2*>(&lA[row][k4]) =
          *reinterpret_cast<const uint2*>(arow + k0 + k4);
    }
#pragma unroll
    for (int i = 0; i < 4; ++i) {
      int c = tid + i * 512;
      int n  = c >> 2;
      int k8 = (c & 3) << 3;
      *reinterpret_cast<uint4*>(&lW[n][k8]) =
          *reinterpret_cast<const uint4*>(Wb + (size_t)n * 512 + k0 + k8);
    }
    __syncthreads();
    bf16x8 af[4], bw[4];
#pragma unroll
    for (int t = 0; t < 4; ++t) {
      af[t] = *reinterpret_cast<const bf16x8*>(&lA[t * 16 + lr][lk]);
      bw[t] = *reinterpret_cast<const bf16x8*>(&lW[w * 64 + t * 16 + lr][lk]);
    }
#pragma unroll
    for (int mi = 0; mi < 4; ++mi)
#pragma unroll
      for (int nj = 0; nj < 4; ++nj)
        acc[mi][nj] = __builtin_amdgcn_mfma_f32_16x16x32_bf16(af[mi], bw[nj], acc[mi][nj], 0, 0, 0);
    __syncthreads();
  }

#pragma unroll
  for (int mi = 0; mi < 4; ++mi)
#pragma unroll
    for (int nj = 0; nj < 4; ++nj) {
#pragma unroll
      for (int j = 0; j < 4; ++j) {
        size_t r = m0 + mi * 16 + ((lane >> 4) << 2) + j;
        int cc = w * 64 + nj * 16 + lr;
        ((float*)(Cb + r * SLOT))[cc] = acc[mi][nj][j];
      }
    }
}

// ---------------------------------------------------------------------------
extern "C" void kernel_launch(void* const* d_in, const int* in_sizes, int n_in,
                              void* d_out, int out_size, void* d_ws, size_t ws_size,
                              hipStream_t stream)
{
  (void)in_sizes; (void)n_in; (void)out_size; (void)ws_size;
  const float* ipt   = (const float*)d_in[0];
  const float* Wq    = (const float*)d_in[1];
  const float* Wkv   = (const float*)d_in[2];
  const float* Wpost = (const float*)d_in[3];
  const float* pa    = (const float*)d_in[4];
  char*  outB = (char*)d_out;
  u16*   wsb  = (u16*)d_ws;

  // weights -> bf16
  conv_bf16<<<128, 256, 0, stream>>>(Wq,    wsb + WQ_OFF,    32768);
  conv_bf16<<<256, 256, 0, stream>>>(Wkv,   wsb + WKV_OFF,   65536);
  conv_bf16<<<128, 256, 0, stream>>>(Wpost, wsb + WPOST_OFF, 32768);

  // Q = prelu(ipt[0:96] @ Wq^T) -> bf16 into d_out slots (XCD-swizzled grid)
  mfma_gemm<2, 1, 1><<<3072, 256, 0, stream>>>(ipt, wsb + WQ_OFF, outB, 512, pa);
  // KV = prelu(ipt[96:104] @ Wkv^T) -> bf16 linear into ws
  mfma_gemm<1, 1, 0><<<dim3(8, 64), 256, 0, stream>>>(ipt + 50331648ll, wsb + WKV_OFF,
                                                      wsb + KV_OFF, 1024, pa);
  // attention + softmax + out_pre (bf16, in place) + head means
  attn_kernel<<<1024, 256, 0, stream>>>(wsb + KV_OFF, outB);
  // out = out_pre @ Wpost^T (fp32 into same slots)
  post_gemm<<<1536, 512, 0, stream>>>(outB, wsb + WPOST_OFF);
}